// Round 13
// baseline (76.565 us; speedup 1.0000x reference)
//
#include <hip/hip_runtime.h>
#include <hip/hip_bf16.h>

// PseudoTripletLoss on MI355X (gfx950)
// loss = sum_{i<j} [ same ? relu(1-s) : relu(s-0.1) ] / (n(n-1))
//
// Decomposition (R13): label-blind main GEMM + tiny same-label correction.
//   loss*n(n-1) = sum_{i<j,all} relu(s-0.1)                      [K2, no labels]
//               + sum_{i<j,same} (relu(1-s) - relu(s-0.1))       [K_corr, ~332k pairs]
// K1: row-normalize fp32 -> bf16 en
// K_count: label histogram + prefix (1 block, deterministic)
// K_compact: stable per-label index compaction (NLAB blocks, ballot-based)
// K_corr: per-label pair sums, rows gathered to fp32 LDS (NLAB blocks)
// K2: R6-best 544 triangular blocks, LDS-staged MFMA, 3-op/elem epilogue
// K3: deterministic reduce of (Tc + NLAB) partials

typedef __attribute__((ext_vector_type(8))) short short8;
typedef __attribute__((ext_vector_type(4))) float f32x4;

#define DIM 128
#define MARGIN 0.1f
#define CHUNK 4
#define NLAB 100
#define CR 48        // corr row-chunk
#define PD 132       // corr LDS row stride (floats): 132%32=4 -> bank spread

typedef const void __attribute__((address_space(1)))* gas_ptr;
typedef void __attribute__((address_space(3)))* las_ptr;

static __device__ __forceinline__ void load16_to_lds(const void* g, void* l) {
    __builtin_amdgcn_global_load_lds((gas_ptr)g, (las_ptr)l, 16, 0, 0);
}

static __device__ __forceinline__ unsigned short f2bf(float f) {
    unsigned int u = __builtin_bit_cast(unsigned int, f);
    u += 0x7FFFu + ((u >> 16) & 1u);
    return (unsigned short)(u >> 16);
}

static __device__ __forceinline__ void stage64(const short* __restrict__ en, int row0,
                                               short* buf, int tid) {
    const char* src = (const char*)(en + (size_t)row0 * DIM);
    char* dst = (char*)buf;
    const int r_lo = tid >> 4;
    const int s    = tid & 15;
    #pragma unroll
    for (int p = 0; p < 4; ++p) {
        const int r  = p * 16 + r_lo;
        const int sc = (s ^ (r & 7)) << 4;
        load16_to_lds(src + (size_t)r * 256 + sc, dst + r * 256 + s * 16);
    }
}

static __device__ __forceinline__ short8 read_frag(const short* buf, int row, int slot) {
    const int ps = slot ^ (row & 7);
    return *(const short8*)(buf + row * DIM + ps * 8);
}

// ---------------- K1: normalize rows -> packed bf16 ----------------
__global__ void __launch_bounds__(256) norm_bf16_kernel(const float* __restrict__ e,
                                                        unsigned int* __restrict__ en_packed) {
    const int row  = blockIdx.x * 4 + (threadIdx.x >> 6);
    const int lane = threadIdx.x & 63;
    const float2 v = *reinterpret_cast<const float2*>(e + row * DIM + lane * 2);
    float s = v.x * v.x + v.y * v.y;
    #pragma unroll
    for (int off = 32; off; off >>= 1) s += __shfl_xor(s, off, 64);
    const float scale = 1.0f / fmaxf(sqrtf(s), 1e-8f);
    const unsigned int lo = f2bf(v.x * scale);
    const unsigned int hi = f2bf(v.y * scale);
    en_packed[row * (DIM / 2) + lane] = (hi << 16) | lo;
}

// ---------------- K_count: histogram + prefix (1 block) ----------------
__global__ void __launch_bounds__(256) count_kernel(const int* __restrict__ labels, int n,
                                                    int* __restrict__ starts) {
    __shared__ int hist[NLAB];
    for (int i = threadIdx.x; i < NLAB; i += 256) hist[i] = 0;
    __syncthreads();
    for (int i = threadIdx.x; i < n; i += 256) atomicAdd(&hist[labels[i]], 1);
    __syncthreads();
    if (threadIdx.x == 0) {
        int acc = 0;
        for (int c = 0; c < NLAB; ++c) { starts[c] = acc; acc += hist[c]; }
        starts[NLAB] = acc;
    }
}

// ---------------- K_compact: stable compaction (NLAB blocks) ----------------
__global__ void __launch_bounds__(256) compact_kernel(const int* __restrict__ labels, int n,
                                                      const int* __restrict__ starts,
                                                      int* __restrict__ perm) {
    const int c    = blockIdx.x;
    const int tid  = threadIdx.x;
    const int lane = tid & 63;
    const int wid  = tid >> 6;
    __shared__ int wcnt[4];
    __shared__ int running;
    if (tid == 0) running = 0;
    __syncthreads();
    const int base_c = starts[c];
    for (int base = 0; base < n; base += 256) {
        const int i = base + tid;
        const bool pred = (i < n) && (labels[i] == c);
        const unsigned long long mask = __ballot(pred);
        const int myrank = __popcll(mask & ((1ULL << lane) - 1ULL));
        if (lane == 0) wcnt[wid] = __popcll(mask);
        __syncthreads();
        int woff = 0;
        #pragma unroll
        for (int w = 0; w < 4; ++w) woff += (w < wid) ? wcnt[w] : 0;
        const int tot = wcnt[0] + wcnt[1] + wcnt[2] + wcnt[3];
        if (pred) perm[base_c + running + woff + myrank] = i;
        __syncthreads();
        if (tid == 0) running += tot;
        __syncthreads();
    }
}

// ---------------- K_corr: same-label pair correction (NLAB blocks) ----------------
static __device__ __forceinline__ void stage_rows_f32(const short* __restrict__ en,
                                                      const int* __restrict__ idx, int nu,
                                                      float* __restrict__ L, int tid) {
    for (int q = tid; q < nu * 16; q += 256) {
        const int k = q >> 4, t = q & 15;
        const int row = idx[k];
        const short8 v = *(const short8*)(en + (size_t)row * DIM + t * 8);
        #pragma unroll
        for (int e = 0; e < 8; ++e) {
            const unsigned int u = ((unsigned int)(unsigned short)v[e]) << 16;
            L[k * PD + t * 8 + e] = __builtin_bit_cast(float, u);
        }
    }
}

__global__ void __launch_bounds__(256) corr_kernel(const short* __restrict__ en,
                                                   const int* __restrict__ starts,
                                                   const int* __restrict__ perm,
                                                   float* __restrict__ outc) {
    __shared__ float LA[CR * PD];
    __shared__ float LB[CR * PD];
    __shared__ float wsum[4];
    const int c   = blockIdx.x;
    const int s0  = starts[c];
    const int nc  = starts[c + 1] - s0;
    const int tid = threadIdx.x;

    float acc = 0.0f;
    for (int cu = 0; cu < nc; cu += CR) {
        const int nu = min(CR, nc - cu);
        __syncthreads();                       // prior readers of LA done
        stage_rows_f32(en, perm + s0 + cu, nu, LA, tid);
        for (int cv = cu; cv < nc; cv += CR) {
            const int nv = min(CR, nc - cv);
            __syncthreads();                   // prior readers of LB done / LA staged
            const float* B = LA;
            if (cv > cu) { stage_rows_f32(en, perm + s0 + cv, nv, LB, tid); B = LB; }
            __syncthreads();                   // staging complete
            const bool tri = (cv == cu);
            const float inv_nv = 1.0f / (float)nv;
            for (int p = tid; p < nu * nv; p += 256) {
                int u = (int)((float)p * inv_nv);
                int v = p - u * nv;
                if (v < 0)        { --u; v += nv; }
                else if (v >= nv) { ++u; v -= nv; }
                if (!tri || u < v) {
                    const float* pa = &LA[u * PD];
                    const float* pb = &B[v * PD];
                    float s = 0.0f;
                    #pragma unroll
                    for (int d = 0; d < DIM; d += 4) {
                        const f32x4 va = *(const f32x4*)(pa + d);
                        const f32x4 vb = *(const f32x4*)(pb + d);
                        s += va[0] * vb[0] + va[1] * vb[1] + va[2] * vb[2] + va[3] * vb[3];
                    }
                    acc += fmaxf(1.0f - s, 0.0f) - fmaxf(s - MARGIN, 0.0f);
                }
            }
        }
    }

    #pragma unroll
    for (int off = 32; off; off >>= 1) acc += __shfl_down(acc, off, 64);
    if ((tid & 63) == 0) wsum[tid >> 6] = acc;
    __syncthreads();
    if (tid == 0) outc[c] = wsum[0] + wsum[1] + wsum[2] + wsum[3];
}

// ---------------- K2: label-blind triangular subtile GEMM ----------------
__global__ void __launch_bounds__(256, 3)
tri_loss_kernel(const short* __restrict__ en, float* __restrict__ partials, int nt) {
    __shared__ __align__(16) short buf[2][64 * DIM];   // 2 x 16 KB
    __shared__ float wsum[4];

    int t  = blockIdx.x;
    int bi = 0, cnt = (nt + CHUNK - 1) / CHUNK;
    #pragma unroll 1
    while (t >= cnt) { t -= cnt; ++bi; cnt = (nt - bi + CHUNK - 1) / CHUNK; }
    const int jbase = bi + t * CHUNK;
    const int nsub  = 2 * min(CHUNK, nt - jbase);

    const int tid  = threadIdx.x;
    const int lane = tid & 63;
    const int wid  = tid >> 6;          // 4 waves = 2x2 over (128 rows x 64 cols)
    const int wr   = wid >> 1, wc = wid & 1;
    const int lm   = lane & 15;
    const int hi   = lane >> 4;
    const int rb   = hi * 4;

    stage64(en, bi * 128,      &buf[0][0], tid);
    stage64(en, bi * 128 + 64, &buf[1][0], tid);

    const int r0w = bi * 128 + wr * 64;
    __syncthreads();                    // A staged

    short8 a[4][4];
    const short* Abuf = &buf[wr][0];
    #pragma unroll
    for (int m = 0; m < 4; ++m)
        #pragma unroll
        for (int ks = 0; ks < 4; ++ks)
            a[m][ks] = read_frag(Abuf, m * 16 + lm, hi + ks * 4);

    __syncthreads();                    // A reads done -> bufs reusable

    stage64(en, jbase * 128, &buf[0][0], tid);
    __syncthreads();                    // B0 staged

    f32x4 vsum = (f32x4){0.0f, 0.0f, 0.0f, 0.0f};

    #pragma unroll 1
    for (int s = 0; s < nsub; ++s) {
        const short* cur = &buf[s & 1][0];
        if (s + 1 < nsub)
            stage64(en, jbase * 128 + (s + 1) * 64, &buf[(s + 1) & 1][0], tid);

        f32x4 acc[4][2] = {};
        #pragma unroll
        for (int ks = 0; ks < 4; ++ks) {
            short8 b[2];
            b[0] = read_frag(cur, wc * 32 + lm,      hi + ks * 4);
            b[1] = read_frag(cur, wc * 32 + 16 + lm, hi + ks * 4);
            #pragma unroll
            for (int m = 0; m < 4; ++m)
                #pragma unroll
                for (int n = 0; n < 2; ++n)
                    acc[m][n] = __builtin_amdgcn_mfma_f32_16x16x32_bf16(a[m][ks], b[n], acc[m][n], 0, 0, 0);
        }

        // label-blind epilogue: 3 VALU/elem off-diag
        if ((jbase == bi) && (s < 2)) {          // diagonal subtile: i<j mask
            const int c0 = jbase * 128 + s * 64 + wc * 32;
            #pragma unroll
            for (int m = 0; m < 4; ++m)
                #pragma unroll
                for (int n = 0; n < 2; ++n) {
                    const f32x4 sv = acc[m][n] - MARGIN;
                    const int jj = c0 + n * 16 + lm;
                    #pragma unroll
                    for (int r = 0; r < 4; ++r) {
                        const int ii = r0w + m * 16 + rb + r;
                        const float tv = fmaxf(sv[r], 0.0f);
                        vsum[r] += (ii < jj) ? tv : 0.0f;
                    }
                }
        } else {
            #pragma unroll
            for (int m = 0; m < 4; ++m)
                #pragma unroll
                for (int n = 0; n < 2; ++n) {
                    const f32x4 sv = acc[m][n] - MARGIN;
                    #pragma unroll
                    for (int r = 0; r < 4; ++r)
                        vsum[r] += fmaxf(sv[r], 0.0f);
                }
        }
        __syncthreads();
    }

    float lsum = vsum[0] + vsum[1] + vsum[2] + vsum[3];
    #pragma unroll
    for (int off = 32; off; off >>= 1) lsum += __shfl_down(lsum, off, 64);
    if (lane == 0) wsum[wid] = lsum;
    __syncthreads();
    if (tid == 0) partials[blockIdx.x] = wsum[0] + wsum[1] + wsum[2] + wsum[3];
}

// ---------------- K3: final deterministic reduce ----------------
__global__ void __launch_bounds__(256) final_reduce_kernel(const float* __restrict__ partials,
                                                           float* __restrict__ out,
                                                           int n, float inv_denom) {
    float s = 0.0f;
    for (int i = threadIdx.x; i < n; i += 256) s += partials[i];
    #pragma unroll
    for (int off = 32; off; off >>= 1) s += __shfl_xor(s, off, 64);
    __shared__ float wsum[4];
    if ((threadIdx.x & 63) == 0) wsum[threadIdx.x >> 6] = s;
    __syncthreads();
    if (threadIdx.x == 0) out[0] = (wsum[0] + wsum[1] + wsum[2] + wsum[3]) * inv_denom;
}

extern "C" void kernel_launch(void* const* d_in, const int* in_sizes, int n_in,
                              void* d_out, int out_size, void* d_ws, size_t ws_size,
                              hipStream_t stream) {
    const float* emb    = (const float*)d_in[0];
    const int*   labels = (const int*)d_in[1];
    float*       out    = (float*)d_out;

    const int n  = in_sizes[1];      // 8192
    const int nt = n / 128;          // 64 strips

    int Tc = 0;                      // 544 blocks at CHUNK=4
    for (int i = 0; i < nt; ++i) Tc += (nt - i + CHUNK - 1) / CHUNK;

    char* ws = (char*)d_ws;
    unsigned int* en_packed = (unsigned int*)ws;                       // 2 MB
    short*        en        = (short*)ws;
    float*        partials  = (float*)(ws + (size_t)n * DIM * 2);      // Tc + NLAB floats
    int*          starts    = (int*)(partials + Tc + NLAB);            // NLAB+1 ints
    int*          perm      = starts + (NLAB + 1);                     // n ints

    norm_bf16_kernel<<<n / 4, 256, 0, stream>>>(emb, en_packed);
    count_kernel<<<1, 256, 0, stream>>>(labels, n, starts);
    compact_kernel<<<NLAB, 256, 0, stream>>>(labels, n, starts, perm);
    corr_kernel<<<NLAB, 256, 0, stream>>>(en, starts, perm, partials + Tc);
    tri_loss_kernel<<<Tc, 256, 0, stream>>>(en, partials, nt);

    const float inv_denom = (float)(1.0 / ((double)n * (double)(n - 1)));
    final_reduce_kernel<<<1, 256, 0, stream>>>(partials, out, Tc + NLAB, inv_denom);
}

// Round 14
// 57.842 us; speedup vs baseline: 1.3237x; 1.3237x over previous
//
#include <hip/hip_runtime.h>
#include <hip/hip_bf16.h>

// PseudoTripletLoss on MI355X (gfx950)
// loss = sum_{i<j} [ same ? relu(1-s) : relu(s-0.1) ] / (n(n-1))
//
// R14: label-SORTED main GEMM (no correction kernels).
//  - prep_kernel (fat): blocks <n/4 row-normalize fp32->bf16 `en`;
//    blocks >=n/4 (one per label) build a stable permutation `perm` sorting
//    rows by label (per-block LDS histogram + prefix + per-wave ballot
//    compact, deterministic) and permuted labels `plab`.
//  - tri_loss: 544 triangular blocks over PERMUTED rows (gather via perm in
//    the global_load_lds source address). Classes are contiguous, so only
//    subtiles whose row/col class ranges overlap need the label-aware
//    epilogue (~6%); everything else is the 3-op label-blind form.
//    Diagonal subtiles apply the strict i<j mask (permuted space = valid
//    pair enumeration; unordered-pair set is permutation-invariant).
//  - final_reduce: deterministic single-block sum.

typedef __attribute__((ext_vector_type(8))) short short8;
typedef __attribute__((ext_vector_type(4))) float f32x4;

#define DIM 128
#define MARGIN 0.1f
#define CHUNK 4
#define NLAB 100
#define WCAP 160     // per-wave compact capacity (quarter-class max ~45)

typedef const void __attribute__((address_space(1)))* gas_ptr;
typedef void __attribute__((address_space(3)))* las_ptr;

static __device__ __forceinline__ void load16_to_lds(const void* g, void* l) {
    __builtin_amdgcn_global_load_lds((gas_ptr)g, (las_ptr)l, 16, 0, 0);
}

static __device__ __forceinline__ unsigned short f2bf(float f) {
    unsigned int u = __builtin_bit_cast(unsigned int, f);
    u += 0x7FFFu + ((u >> 16) & 1u);
    return (unsigned short)(u >> 16);
}

// Stage 64 PERMUTED rows (perm[row0..row0+64)) of en into a 16 KB LDS buf.
// XOR involution on the SOURCE column; LDS dest lane-linear (global_load_lds
// requirement). Gather is free: source address is per-lane.
static __device__ __forceinline__ void stage64p(const short* __restrict__ en,
                                                const int* __restrict__ perm, int row0,
                                                short* buf, int tid) {
    char* dst = (char*)buf;
    const int r_lo = tid >> 4;
    const int slot = tid & 15;
    #pragma unroll
    for (int p = 0; p < 4; ++p) {
        const int r    = p * 16 + r_lo;
        const int srow = perm[row0 + r];
        const int sc   = (slot ^ (r & 7)) << 4;
        load16_to_lds((const char*)(en + (size_t)srow * DIM) + sc,
                      dst + r * 256 + slot * 16);
    }
}

static __device__ __forceinline__ short8 read_frag(const short* buf, int row, int slot) {
    const int ps = slot ^ (row & 7);
    return *(const short8*)(buf + row * DIM + ps * 8);
}

// ---------------- fat prep: norm (blocks < n/4) + label compact (blocks >= n/4) ----------------
__global__ void __launch_bounds__(256) prep_kernel(const float* __restrict__ e,
                                                   const int* __restrict__ labels, int n,
                                                   unsigned int* __restrict__ en_packed,
                                                   int* __restrict__ perm,
                                                   int* __restrict__ plab) {
    const int tid  = threadIdx.x;
    const int lane = tid & 63;
    const int wid  = tid >> 6;
    const int nb_norm = n >> 2;

    if ((int)blockIdx.x < nb_norm) {
        // ---- norm role: 4 rows per block, one wave per row ----
        const int row = blockIdx.x * 4 + wid;
        const float2 v = *reinterpret_cast<const float2*>(e + (size_t)row * DIM + lane * 2);
        float s = v.x * v.x + v.y * v.y;
        #pragma unroll
        for (int off = 32; off; off >>= 1) s += __shfl_xor(s, off, 64);
        const float scale = 1.0f / fmaxf(sqrtf(s), 1e-8f);
        const unsigned int lo = f2bf(v.x * scale);
        const unsigned int hi = f2bf(v.y * scale);
        en_packed[row * (DIM / 2) + lane] = (hi << 16) | lo;
        return;
    }

    // ---- compact role: one class per block, stable & deterministic ----
    const int c = (int)blockIdx.x - nb_norm;
    __shared__ int hist[NLAB];
    __shared__ int wlist[4][WCAP];
    __shared__ int wcnt[4];
    __shared__ int red[4];

    for (int i = tid; i < NLAB; i += 256) hist[i] = 0;
    __syncthreads();
    for (int i = tid; i < n; i += 256) atomicAdd(&hist[labels[i]], 1);
    __syncthreads();

    // starts_c = sum_{t<c} hist[t]
    int v = (tid < c && tid < NLAB) ? hist[tid] : 0;
    #pragma unroll
    for (int off = 32; off; off >>= 1) v += __shfl_xor(v, off, 64);
    if (lane == 0) red[wid] = v;
    __syncthreads();
    const int starts_c = red[0] + red[1] + red[2] + red[3];

    // per-wave stable ballot compact over this wave's quarter of the rows
    const int nq    = n >> 2;
    const int wbase = wid * nq;
    int running = 0;
    #pragma unroll 1
    for (int it = 0; it < nq / 64; ++it) {
        const int i = wbase + it * 64 + lane;
        const bool pred = (labels[i] == c);
        const unsigned long long mask = __ballot(pred);
        const int rank = __popcll(mask & ((1ULL << lane) - 1ULL));
        if (pred) {
            const int p = running + rank;
            if (p < WCAP) wlist[wid][p] = i;
        }
        running += __popcll(mask);
    }
    if (lane == 0) wcnt[wid] = min(running, WCAP);
    __syncthreads();

    int off = starts_c;
    #pragma unroll
    for (int w = 0; w < 4; ++w) off += (w < wid) ? wcnt[w] : 0;
    const int cw = wcnt[wid];
    for (int k = lane; k < cw; k += 64) {
        perm[off + k] = wlist[wid][k];
        plab[off + k] = c;
    }
}

// ---------------- K2': label-sorted triangular subtile GEMM ----------------
__global__ void __launch_bounds__(256, 3)
tri_loss_kernel(const short* __restrict__ en, const int* __restrict__ perm,
                const int* __restrict__ plab, float* __restrict__ partials, int nt) {
    __shared__ __align__(16) short buf[2][64 * DIM];   // 2 x 16 KB
    __shared__ float wsum[4];

    // exact (strip bi, chunk t) decode
    int t  = blockIdx.x;
    int bi = 0, cnt = (nt + CHUNK - 1) / CHUNK;
    #pragma unroll 1
    while (t >= cnt) { t -= cnt; ++bi; cnt = (nt - bi + CHUNK - 1) / CHUNK; }
    const int jbase = bi + t * CHUNK;
    const int jb128 = jbase * 128;
    const int nsub  = 2 * min(CHUNK, nt - jbase);

    const int tid  = threadIdx.x;
    const int lane = tid & 63;
    const int wid  = tid >> 6;          // 4 waves = 2x2 over (128 rows x 64 cols)
    const int wr   = wid >> 1, wc = wid & 1;
    const int lm   = lane & 15;
    const int hi   = lane >> 4;
    const int rb   = hi * 4;

    stage64p(en, perm, bi * 128,      &buf[0][0], tid);
    stage64p(en, perm, bi * 128 + 64, &buf[1][0], tid);

    // permuted row labels + block row-class range (uniform)
    const int r0w = bi * 128 + wr * 64;
    int liv[4][4];
    #pragma unroll
    for (int m = 0; m < 4; ++m) {
        const int4 lv = *(const int4*)(plab + r0w + m * 16 + rb);
        liv[m][0] = lv.x; liv[m][1] = lv.y; liv[m][2] = lv.z; liv[m][3] = lv.w;
    }
    const int rowlo_c = plab[bi * 128];
    const int rowhi_c = plab[bi * 128 + 127];

    __syncthreads();                    // A staged

    short8 a[4][4];
    const short* Abuf = &buf[wr][0];
    #pragma unroll
    for (int m = 0; m < 4; ++m)
        #pragma unroll
        for (int ks = 0; ks < 4; ++ks)
            a[m][ks] = read_frag(Abuf, m * 16 + lm, hi + ks * 4);

    __syncthreads();                    // A reads done -> bufs reusable

    stage64p(en, perm, jb128, &buf[0][0], tid);
    __syncthreads();                    // B0 staged

    f32x4 vsum = (f32x4){0.0f, 0.0f, 0.0f, 0.0f};

    #pragma unroll 1
    for (int s = 0; s < nsub; ++s) {
        const short* cur = &buf[s & 1][0];
        if (s + 1 < nsub)
            stage64p(en, perm, jb128 + (s + 1) * 64, &buf[(s + 1) & 1][0], tid);

        f32x4 acc[4][2] = {};
        #pragma unroll
        for (int ks = 0; ks < 4; ++ks) {
            short8 b[2];
            b[0] = read_frag(cur, wc * 32 + lm,      hi + ks * 4);
            b[1] = read_frag(cur, wc * 32 + 16 + lm, hi + ks * 4);
            #pragma unroll
            for (int m = 0; m < 4; ++m)
                #pragma unroll
                for (int n = 0; n < 2; ++n)
                    acc[m][n] = __builtin_amdgcn_mfma_f32_16x16x32_bf16(a[m][ks], b[n], acc[m][n], 0, 0, 0);
        }

        const int  c0     = jb128 + s * 64 + wc * 32;
        const bool isdiag = (jbase == bi) && (s < 2);
        const int  ccl    = plab[jb128 + s * 64];
        const int  cch    = plab[jb128 + s * 64 + 63];
        const bool labneed = isdiag || (ccl <= rowhi_c && cch >= rowlo_c);

        if (!labneed) {
            // label-blind: 3 VALU/elem  (no same-class pairs possible here)
            #pragma unroll
            for (int m = 0; m < 4; ++m)
                #pragma unroll
                for (int n = 0; n < 2; ++n) {
                    const f32x4 sv = acc[m][n] - MARGIN;
                    #pragma unroll
                    for (int r = 0; r < 4; ++r)
                        vsum[r] += fmaxf(sv[r], 0.0f);
                }
        } else {
            int labj[2];
            labj[0] = plab[c0 + lm];
            labj[1] = plab[c0 + 16 + lm];
            if (isdiag) {
                #pragma unroll
                for (int m = 0; m < 4; ++m)
                    #pragma unroll
                    for (int n = 0; n < 2; ++n) {
                        const f32x4 sv = acc[m][n];
                        const int jj = c0 + n * 16 + lm;
                        #pragma unroll
                        for (int r = 0; r < 4; ++r) {
                            const int ii = r0w + m * 16 + rb + r;
                            const float bv = fmaxf(sv[r] - MARGIN, 0.0f);
                            const float tv = (liv[m][r] == labj[n]) ? (1.0f - sv[r]) : bv;
                            vsum[r] += (ii < jj) ? tv : 0.0f;
                        }
                    }
            } else {
                #pragma unroll
                for (int m = 0; m < 4; ++m)
                    #pragma unroll
                    for (int n = 0; n < 2; ++n) {
                        const f32x4 sv = acc[m][n];
                        #pragma unroll
                        for (int r = 0; r < 4; ++r) {
                            const float bv = fmaxf(sv[r] - MARGIN, 0.0f);
                            vsum[r] += (liv[m][r] == labj[n]) ? (1.0f - sv[r]) : bv;
                        }
                    }
            }
        }
        __syncthreads();
    }

    float lsum = vsum[0] + vsum[1] + vsum[2] + vsum[3];
    #pragma unroll
    for (int off = 32; off; off >>= 1) lsum += __shfl_down(lsum, off, 64);
    if (lane == 0) wsum[wid] = lsum;
    __syncthreads();
    if (tid == 0) partials[blockIdx.x] = wsum[0] + wsum[1] + wsum[2] + wsum[3];
}

// ---------------- K3: final deterministic reduce ----------------
__global__ void __launch_bounds__(256) final_reduce_kernel(const float* __restrict__ partials,
                                                           float* __restrict__ out,
                                                           int n, float inv_denom) {
    float s = 0.0f;
    for (int i = threadIdx.x; i < n; i += 256) s += partials[i];
    #pragma unroll
    for (int off = 32; off; off >>= 1) s += __shfl_xor(s, off, 64);
    __shared__ float wsum[4];
    if ((threadIdx.x & 63) == 0) wsum[threadIdx.x >> 6] = s;
    __syncthreads();
    if (threadIdx.x == 0) out[0] = (wsum[0] + wsum[1] + wsum[2] + wsum[3]) * inv_denom;
}

extern "C" void kernel_launch(void* const* d_in, const int* in_sizes, int n_in,
                              void* d_out, int out_size, void* d_ws, size_t ws_size,
                              hipStream_t stream) {
    const float* emb    = (const float*)d_in[0];
    const int*   labels = (const int*)d_in[1];
    float*       out    = (float*)d_out;

    const int n  = in_sizes[1];      // 8192
    const int nt = n / 128;          // 64 strips

    int Tc = 0;                      // 544 blocks at CHUNK=4
    for (int i = 0; i < nt; ++i) Tc += (nt - i + CHUNK - 1) / CHUNK;

    char* ws = (char*)d_ws;
    unsigned int* en_packed = (unsigned int*)ws;                         // 2 MB
    short*        en        = (short*)ws;
    float*        partials  = (float*)(ws + (size_t)n * DIM * 2);        // Tc floats
    int*          perm      = (int*)(ws + (size_t)n * DIM * 2 + 16384);  // n ints
    int*          plab      = perm + n;                                  // n ints

    prep_kernel<<<n / 4 + NLAB, 256, 0, stream>>>(emb, labels, n, en_packed, perm, plab);

    tri_loss_kernel<<<Tc, 256, 0, stream>>>(en, perm, plab, partials, nt);

    const float inv_denom = (float)(1.0 / ((double)n * (double)(n - 1)));
    final_reduce_kernel<<<1, 256, 0, stream>>>(partials, out, Tc, inv_denom);
}

// Round 15
// 30.969 us; speedup vs baseline: 2.4723x; 1.8677x over previous
//
#include <hip/hip_runtime.h>
#include <hip/hip_bf16.h>

// PseudoTripletLoss on MI355X (gfx950)
// loss = sum_{i<j} [ same ? relu(1-s) : relu(s-0.1) ] / (n(n-1))
//
// R15: revert to R6-proven structure (544 triangular blocks, CHUNK=4,
// 64x128 B subtiles double-buffered via coalesced global_load_lds, XOR
// swizzle, label-aware epilogue) with ONE change: 512-thread blocks
// (8 waves, wave tile 32x32) -> 2 blocks/CU x 8 waves = 4 waves/SIMD from
// two independently-phased blocks; halves per-wave epilogue tail and
// per-wave registers (no spill at the 128-VGPR/4-wave tier).

typedef __attribute__((ext_vector_type(8))) short short8;
typedef __attribute__((ext_vector_type(4))) float f32x4;

#define DIM 128
#define MARGIN 0.1f
#define CHUNK 4      // 128-col tiles per block -> up to 8 subtiles of 64 cols

typedef const void __attribute__((address_space(1)))* gas_ptr;
typedef void __attribute__((address_space(3)))* las_ptr;

static __device__ __forceinline__ void load16_to_lds(const void* g, void* l) {
    __builtin_amdgcn_global_load_lds((gas_ptr)g, (las_ptr)l, 16, 0, 0);
}

static __device__ __forceinline__ unsigned short f2bf(float f) {
    unsigned int u = __builtin_bit_cast(unsigned int, f);
    u += 0x7FFFu + ((u >> 16) & 1u);   // round-to-nearest-even
    return (unsigned short)(u >> 16);
}

// Stage a 64x128 bf16 tile into a 16 KB LDS buf. 512-thread version:
// 2 passes x (32 rows x 16 slots). XOR involution on SOURCE column; LDS dest
// stays lane-linear within each wave (base + lane*16) as global_load_lds
// requires.
static __device__ __forceinline__ void stage64(const short* __restrict__ en, int row0,
                                               short* buf, int tid) {
    const char* src = (const char*)(en + (size_t)row0 * DIM);
    char* dst = (char*)buf;
    const int r_lo = tid >> 4;       // 0..31
    const int s    = tid & 15;       // 16B slot
    #pragma unroll
    for (int p = 0; p < 2; ++p) {
        const int r  = p * 32 + r_lo;
        const int sc = (s ^ (r & 7)) << 4;
        load16_to_lds(src + (size_t)r * 256 + sc, dst + r * 256 + s * 16);
    }
}

static __device__ __forceinline__ short8 read_frag(const short* buf, int row, int slot) {
    const int ps = slot ^ (row & 7);
    return *(const short8*)(buf + row * DIM + ps * 8);
}

// ---------------- K1: normalize rows -> packed bf16 ----------------
__global__ void __launch_bounds__(256) norm_bf16_kernel(const float* __restrict__ e,
                                                        unsigned int* __restrict__ en_packed) {
    const int row  = blockIdx.x * 4 + (threadIdx.x >> 6);
    const int lane = threadIdx.x & 63;
    const float2 v = *reinterpret_cast<const float2*>(e + row * DIM + lane * 2);
    float s = v.x * v.x + v.y * v.y;
    #pragma unroll
    for (int off = 32; off; off >>= 1) s += __shfl_xor(s, off, 64);
    const float scale = 1.0f / fmaxf(sqrtf(s), 1e-8f);
    const unsigned int lo = f2bf(v.x * scale);
    const unsigned int hi = f2bf(v.y * scale);
    en_packed[row * (DIM / 2) + lane] = (hi << 16) | lo;
}

// ---------------- K2: 8-wave LDS-staged triangular subtile GEMM ----------------
__global__ void __launch_bounds__(512, 4)
tri_loss_kernel(const short* __restrict__ en, const int* __restrict__ labels,
                float* __restrict__ partials, int nt) {
    __shared__ __align__(16) short buf[2][64 * DIM];   // 2 x 16 KB
    __shared__ float wsum[8];

    // exact (strip bi, chunk t) decode: no dead blocks
    int t  = blockIdx.x;
    int bi = 0, cnt = (nt + CHUNK - 1) / CHUNK;
    #pragma unroll 1
    while (t >= cnt) { t -= cnt; ++bi; cnt = (nt - bi + CHUNK - 1) / CHUNK; }
    const int jbase = bi + t * CHUNK;
    const int jb128 = jbase * 128;
    const int nsub  = 2 * min(CHUNK, nt - jbase);

    const int tid  = threadIdx.x;
    const int lane = tid & 63;
    const int wid  = tid >> 6;          // 8 waves = 4x2 over (128 rows x 64 cols)
    const int wr   = wid >> 1;          // 0..3: 32-row band
    const int wc   = wid & 1;           // 0..1: 32-col half
    const int lm   = lane & 15;
    const int hi   = lane >> 4;
    const int rb   = hi * 4;

    // ---- stage A strip halves into the two buffers ----
    stage64(en, bi * 128,      &buf[0][0], tid);
    stage64(en, bi * 128 + 64, &buf[1][0], tid);

    // this wave's 32 rows: labels (static regs)
    const int r0w = bi * 128 + wr * 32;
    int liv[2][4];
    #pragma unroll
    for (int m = 0; m < 2; ++m) {
        const int4 lv = *(const int4*)(labels + r0w + m * 16 + rb);
        liv[m][0] = lv.x; liv[m][1] = lv.y; liv[m][2] = lv.z; liv[m][3] = lv.w;
    }

    __syncthreads();                    // A staged

    // ---- extract A fragments (wave's 32 rows, full K=128): 32 VGPR ----
    short8 a[2][4];
    const short* Abuf = &buf[wr >> 1][0];
    const int rloc = (wr & 1) * 32;
    #pragma unroll
    for (int m = 0; m < 2; ++m)
        #pragma unroll
        for (int ks = 0; ks < 4; ++ks)
            a[m][ks] = read_frag(Abuf, rloc + m * 16 + lm, hi + ks * 4);

    __syncthreads();                    // A reads done -> bufs reusable

    stage64(en, jb128, &buf[0][0], tid);   // first B subtile
    __syncthreads();                    // B0 staged

    f32x4 vsum = (f32x4){0.0f, 0.0f, 0.0f, 0.0f};

    #pragma unroll 1
    for (int s = 0; s < nsub; ++s) {
        const short* cur = &buf[s & 1][0];
        if (s + 1 < nsub)                              // prefetch next subtile
            stage64(en, jb128 + (s + 1) * 64, &buf[(s + 1) & 1][0], tid);

        const int c0 = jb128 + s * 64 + wc * 32;
        int labj[2];
        labj[0] = labels[c0 + lm];
        labj[1] = labels[c0 + 16 + lm];

        f32x4 acc[2][2] = {};
        #pragma unroll
        for (int ks = 0; ks < 4; ++ks) {
            short8 b[2];
            b[0] = read_frag(cur, wc * 32 + lm,      hi + ks * 4);
            b[1] = read_frag(cur, wc * 32 + 16 + lm, hi + ks * 4);
            #pragma unroll
            for (int m = 0; m < 2; ++m)
                #pragma unroll
                for (int n = 0; n < 2; ++n)
                    acc[m][n] = __builtin_amdgcn_mfma_f32_16x16x32_bf16(a[m][ks], b[n], acc[m][n], 0, 0, 0);
        }

        // ---- fused hinge epilogue (C/D map: col = lane&15, row = hi*4 + reg) ----
        if ((jbase == bi) && (s < 2)) {                // diagonal subtile: i<j mask
            #pragma unroll
            for (int m = 0; m < 2; ++m)
                #pragma unroll
                for (int n = 0; n < 2; ++n) {
                    const f32x4 sv   = acc[m][n];
                    const f32x4 base = sv - MARGIN;
                    const f32x4 alt  = 1.0f - sv;
                    const int jj = c0 + n * 16 + lm;
                    #pragma unroll
                    for (int r = 0; r < 4; ++r) {
                        const int ii = r0w + m * 16 + rb + r;
                        const float bv = fmaxf(base[r], 0.0f);
                        const float tv = (liv[m][r] == labj[n]) ? alt[r] : bv;
                        vsum[r] += (ii < jj) ? tv : 0.0f;
                    }
                }
        } else {
            #pragma unroll
            for (int m = 0; m < 2; ++m)
                #pragma unroll
                for (int n = 0; n < 2; ++n) {
                    const f32x4 sv   = acc[m][n];
                    const f32x4 base = sv - MARGIN;
                    const f32x4 alt  = 1.0f - sv;
                    #pragma unroll
                    for (int r = 0; r < 4; ++r) {
                        const float bv = fmaxf(base[r], 0.0f);
                        vsum[r] += (liv[m][r] == labj[n]) ? alt[r] : bv;
                    }
                }
        }
        __syncthreads();   // subtile reads done; next stage landed
    }

    float lsum = vsum[0] + vsum[1] + vsum[2] + vsum[3];
    #pragma unroll
    for (int off = 32; off; off >>= 1) lsum += __shfl_down(lsum, off, 64);
    if (lane == 0) wsum[wid] = lsum;
    __syncthreads();
    if (tid == 0) {
        float b = 0.0f;
        #pragma unroll
        for (int w = 0; w < 8; ++w) b += wsum[w];
        partials[blockIdx.x] = b;
    }
}

// ---------------- K3: final deterministic reduce ----------------
__global__ void __launch_bounds__(256) final_reduce_kernel(const float* __restrict__ partials,
                                                           float* __restrict__ out,
                                                           int n, float inv_denom) {
    float s = 0.0f;
    for (int i = threadIdx.x; i < n; i += 256) s += partials[i];
    #pragma unroll
    for (int off = 32; off; off >>= 1) s += __shfl_xor(s, off, 64);
    __shared__ float wsum[4];
    if ((threadIdx.x & 63) == 0) wsum[threadIdx.x >> 6] = s;
    __syncthreads();
    if (threadIdx.x == 0) out[0] = (wsum[0] + wsum[1] + wsum[2] + wsum[3]) * inv_denom;
}

extern "C" void kernel_launch(void* const* d_in, const int* in_sizes, int n_in,
                              void* d_out, int out_size, void* d_ws, size_t ws_size,
                              hipStream_t stream) {
    const float* emb    = (const float*)d_in[0];
    const int*   labels = (const int*)d_in[1];
    float*       out    = (float*)d_out;

    const int n  = in_sizes[1];      // 8192
    const int nt = n / 128;          // 64 strips

    int Tc = 0;                      // 544 blocks at CHUNK=4
    for (int i = 0; i < nt; ++i) Tc += (nt - i + CHUNK - 1) / CHUNK;

    unsigned int* en_packed = (unsigned int*)d_ws;                 // 2 MB
    short*        en        = (short*)d_ws;
    float*        partials  = (float*)((char*)d_ws + (size_t)n * DIM * 2);

    norm_bf16_kernel<<<n / 4, 256, 0, stream>>>(emb, en_packed);

    tri_loss_kernel<<<Tc, 512, 0, stream>>>(en, labels, partials, nt);

    const float inv_denom = (float)(1.0 / ((double)n * (double)(n - 1)));
    final_reduce_kernel<<<1, 256, 0, stream>>>(partials, out, Tc, inv_denom);
}